// Round 14
// baseline (68.423 us; speedup 1.0000x reference)
//
#include <hip/hip_runtime.h>
#include <hip/hip_bf16.h>

#define CH 384
#define HH 56
#define WW 56
#define HW (HH*WW)      // 3136 = 28*112
#define NN 16
#define BN 112          // pw pix-tile
#define BK 64           // pw k-chunk

#define XRING 6         // dw ring rows: live set = 6 consecutive (reads 4 + stage 2)
#define XRROW 7168      // ring-row bytes: 32 ci x 224 B
#define YSP 34          // ys pitch elems: 32 + 2 pad -> 17-dword stride (odd: bank-rotates)

typedef __attribute__((ext_vector_type(4))) float f32x4;
typedef __attribute__((ext_vector_type(8))) short bf16x8;
typedef __attribute__((ext_vector_type(4))) unsigned int u32x4;

// Prepared weights
__device__ float          g_wdw_eff[CH * 9];   // depthwise: u*mx exact fp32, [o][tap]
__device__ __hip_bfloat16 g_wpw_u[CH * CH];    // pointwise: ternary u exact bf16, [co][ci]
__device__ float          g_mx_pw;             // pointwise scale (epilogue multiply)

// ---------- prep stage A: deterministic per-block |w| partial sums ----------
__global__ __launch_bounds__(256) void partial_kernel(const float* __restrict__ wpw,
                                                      double* __restrict__ part) {
    const int t = threadIdx.x;
    const int base = blockIdx.x * 1536;
    double s = 0.0;
    #pragma unroll
    for (int k = 0; k < 6; ++k) s += (double)fabsf(wpw[base + t + k * 256]);
    #pragma unroll
    for (int off = 32; off > 0; off >>= 1) s += __shfl_down(s, off, 64);
    __shared__ double sred[4];
    if ((t & 63) == 0) sred[t >> 6] = s;
    __syncthreads();
    if (t == 0) part[blockIdx.x] = ((sred[0] + sred[1]) + sred[2]) + sred[3];
}

// ---------- prep stage B: finalize scale (in-order, deterministic) + quantize ----------
__global__ __launch_bounds__(512) void quant_kernel(const float* __restrict__ wdw,
                                                    const float* __restrict__ wpw,
                                                    const double* __restrict__ part) {
    const int t = threadIdx.x;
    __shared__ double pl[96];
    __shared__ float s_scale, s_mx;
    if (t < 96) pl[t] = part[t];
    __syncthreads();
    if (t == 0) {
        double tot = 0.0;
        #pragma unroll
        for (int i = 0; i < 96; ++i) tot += pl[i];   // fixed order
        const float mean = (float)(tot / (double)(CH * CH));
        const float mx   = fmaxf(mean, 1e-5f);
        s_mx = mx;
        s_scale = 1.0f / mx;
    }
    __syncthreads();
    const float scale = s_scale;

    const int base = blockIdx.x * 4096 + t * 8;      // 36*512*8 = 147456 exact
    const float4 a = *reinterpret_cast<const float4*>(wpw + base);
    const float4 b = *reinterpret_cast<const float4*>(wpw + base + 4);
    const float vin[8] = {a.x, a.y, a.z, a.w, b.x, b.y, b.z, b.w};
    bf16x8 uo;
    #pragma unroll
    for (int k = 0; k < 8; ++k) {
        float u = rintf(vin[k] * scale);             // jnp.round == RNE
        u = fminf(1.f, fmaxf(-1.f, u));
        __hip_bfloat16 h = __float2bfloat16(u);      // {-1,0,1} exact in bf16
        uo[k] = *reinterpret_cast<short*>(&h);
    }
    *reinterpret_cast<bf16x8*>(g_wpw_u + base) = uo;

    if (blockIdx.x == 0) {
        if (t == 0) g_mx_pw = s_mx;
        if (t < CH) {
            const float* w = wdw + t * 9;
            float asum = 0.f;
            #pragma unroll
            for (int k = 0; k < 9; ++k) asum += fabsf(w[k]);
            const float mxd = fmaxf(asum / 9.0f, 1e-5f);
            const float scd = 1.0f / mxd;
            #pragma unroll
            for (int k = 0; k < 9; ++k) {
                float u = rintf(w[k] * scd);
                u = fminf(1.f, fmaxf(-1.f, u));
                g_wdw_eff[t * 9 + k] = u * mxd;      // exact product
            }
        }
    }
}

// ---------- kernel 1: depthwise v8.5 — v9 ring/vmcnt skeleton + full-line y writes ----------
// Block = (n, 32-ci group, 14-row quarter): 7 items of 2 out-rows, 6-row LDS
// ring, counted vmcnt (2 stage issues + 1 store per wave per item). Output
// goes through a small ys transpose (pitch 34 = odd-dword, v8-proven
// conflict-free) so the dump writes FULL 64-B lines: thread (px, g) stores
// 16 B at y[px][ci0+g*8]; 4 g-threads cover one aligned line (v8's 16-ci
// blocks wrote 16-B fragments at 768-B stride = ~2x write amplification).
__global__ __launch_bounds__(448, 6) void dw_kernel(const float* __restrict__ x,
                                                    __hip_bfloat16* __restrict__ y) {
    __shared__ __attribute__((aligned(16))) char xs[XRING * XRROW];   // 43008 B
    __shared__ __attribute__((aligned(16))) __hip_bfloat16 ys[112 * YSP]; // 7616 B

    const int bid  = blockIdx.x;
    const int orig = (bid & 7) * 96 + (bid >> 3);    // XCD swizzle, 768 = 8*96
    const int n    = orig / 48;
    const int rem  = orig - n * 48;
    const int cig  = rem >> 2;                       // 0..11
    const int qtr  = rem & 3;                        // 0..3
    const int ci0  = cig * 32;
    const int qb   = qtr * 14;

    const int t    = threadIdx.x;
    const int wv   = t >> 6;
    const int lane = t & 63;

    // stage-role invariants: slot -> (ci, col-chunk); one contiguous row run/ci
    const int slot = wv * 64 + lane;                 // 0..447 (one x-row of 32 ci)
    const int sci  = slot / 14;
    const int scl  = slot - sci * 14;
    const float* xg    = x + ((size_t)n * CH + ci0) * HW;
    const float* sbase = xg + (size_t)sci * HW + scl * 4;
    char* sdst = xs + wv * 1024;                     // + rr*XRROW per stage

    // compute-role: t = cil*14 + rowp*7 + wc
    const int cil  = t / 14;                         // 0..31
    const int rm   = t - cil * 14;
    const int rowp = rm / 7;                         // 0..1
    const int wc   = rm - rowp * 7;                  // 0..6
    const int w0   = wc * 8;

    // dump-role: t = px*4 + g
    const int dpx = t >> 2;                          // 0..111
    const int dg  = t & 3;                           // ci octet
    const int drow = (dpx >= WW) ? 1 : 0;
    const int dw_  = dpx - drow * WW;

    float wt[9];
    {
        const float* wdp = g_wdw_eff + (ci0 + cil) * 9;
        #pragma unroll
        for (int k = 0; k < 9; ++k) wt[k] = wdp[k];
    }

    // ---- prologue: stage x rows qb-1 .. qb+2 (4 issues/wave) ----
    #pragma unroll
    for (int k = 0; k < 4; ++k) {
        int R = qb - 1 + k;
        const int rr = (R + XRING) % XRING;
        R = R < 0 ? 0 : R;
        __builtin_amdgcn_global_load_lds(
            (const __attribute__((address_space(1))) void*)(sbase + (size_t)R * WW),
            (__attribute__((address_space(3))) void*)(sdst + rr * XRROW), 16, 0, 0);
    }

    #pragma unroll
    for (int i = 0; i < 7; ++i) {
        const int h0 = qb + 2 * i;
        if (i < 6) {
            #pragma unroll
            for (int k = 0; k < 2; ++k) {
                int R = h0 + 3 + k;                  // next item's new rows
                const int rr = R % XRING;
                R = R > HH - 1 ? HH - 1 : R;
                __builtin_amdgcn_global_load_lds(
                    (const __attribute__((address_space(1))) void*)(sbase + (size_t)R * WW),
                    (__attribute__((address_space(3))) void*)(sdst + rr * XRROW), 16, 0, 0);
            }
            // retire item i's 2 loads; keep item i+1's 2 (+ older store) in flight
            if (i == 0) asm volatile("s_waitcnt vmcnt(2)" ::: "memory");
            else        asm volatile("s_waitcnt vmcnt(3)" ::: "memory");
        } else {
            asm volatile("s_waitcnt vmcnt(1)" ::: "memory");   // leaves S5; drains L6
        }
        __builtin_amdgcn_s_barrier();
        __builtin_amdgcn_sched_barrier(0);

        // ---- compute: out row h = h0+rowp, 8 px; x rows h-1..h+1 from ring ----
        const int h = h0 + rowp;
        float acc[8] = {0.f, 0.f, 0.f, 0.f, 0.f, 0.f, 0.f, 0.f};
        #pragma unroll
        for (int r = 0; r < 3; ++r) {
            const int rr = (h - 1 + r + XRING) % XRING;
            const char* rp = xs + rr * XRROW + cil * 224 + wc * 32;
            const f32x4 f0 = *reinterpret_cast<const f32x4*>(rp);
            const f32x4 f1 = *reinterpret_cast<const f32x4*>(rp + 16);
            float e0 = 0.f, x9 = 0.f;
            if (wc > 0) e0 = *reinterpret_cast<const float*>(rp - 4);
            if (wc < 6) x9 = *reinterpret_cast<const float*>(rp + 32);
            const float xv[10] = {e0, f0.x, f0.y, f0.z, f0.w,
                                  f1.x, f1.y, f1.z, f1.w, x9};
            const bool dead = (r == 0 && h == 0) || (r == 2 && h == HH - 1);
            #pragma unroll
            for (int d = 0; d < 3; ++d) {
                const float w3 = dead ? 0.f : wt[r * 3 + d];
                #pragma unroll
                for (int j = 0; j < 8; ++j) acc[j] += w3 * xv[j + d];
            }
        }
        // ---- ys transpose write: [px 112][32 ci], odd pitch -> conflict-free ----
        #pragma unroll
        for (int j = 0; j < 8; ++j)
            ys[(rowp * WW + w0 + j) * YSP + cil] = __float2bfloat16(acc[j]);

        asm volatile("s_waitcnt lgkmcnt(0)" ::: "memory");
        __builtin_amdgcn_s_barrier();
        __builtin_amdgcn_sched_barrier(0);

        // ---- dump: thread (px,g): 4x b32 LDS -> one 16B store; 4 g = full line ----
        {
            const unsigned* yp =
                reinterpret_cast<const unsigned*>(ys + dpx * YSP + dg * 8);
            u32x4 v;
            v.x = yp[0]; v.y = yp[1]; v.z = yp[2]; v.w = yp[3];
            *reinterpret_cast<u32x4*>(
                y + ((size_t)n * HW + (size_t)(h0 + drow) * WW + dw_) * CH
                  + ci0 + dg * 8) = v;
        }
        __builtin_amdgcn_sched_barrier(0);           // pin store before next STAGE (vmcnt FIFO)
    }
}

// ---------- kernel 2: pointwise GEMM, global_load_lds-staged B, dbuf ----------
// (verbatim round-12 — proven; consumes y[n][pix][ci])
#define STAGE(B, KC) do {                                                         \
    const int _k0 = (KC) * BK;                                                    \
    _Pragma("unroll")                                                             \
    for (int _i = 0; _i < 4; ++_i) {                                              \
        const int _sb = wv * 4 + _i;                                              \
        if (_sb < 14) {                                                           \
            const int _s  = _sb * 64 + lane;                                      \
            const int _p  = _s >> 3;                                              \
            const int _c8 = (_s & 7) ^ (_p & 7);                                  \
            __builtin_amdgcn_global_load_lds(                                     \
                (const __attribute__((address_space(1))) void*)                  \
                    (yb + (size_t)_p * CH + _k0 + _c8 * 8),                       \
                (__attribute__((address_space(3))) void*)                        \
                    (&blds[(B)][0] + _sb * 512),                                  \
                16, 0, 0);                                                        \
        }                                                                         \
    }                                                                             \
} while (0)

#define LOADA(dst, KC) {                                                          \
    dst[0][0] = *reinterpret_cast<const bf16x8*>(ap0 + (KC) * 64);                \
    dst[0][1] = *reinterpret_cast<const bf16x8*>(ap0 + (KC) * 64 + 32);           \
    dst[1][0] = *reinterpret_cast<const bf16x8*>(ap1 + (KC) * 64);                \
    dst[1][1] = *reinterpret_cast<const bf16x8*>(ap1 + (KC) * 64 + 32); }

__global__ __launch_bounds__(256) void pw_kernel(const __hip_bfloat16* __restrict__ y,
                                                 float* __restrict__ out) {
    __shared__ __attribute__((aligned(16))) __hip_bfloat16 blds[2][BN * BK]; // 2x14336 B

    const int bid  = blockIdx.x;
    const int orig = (bid & 7) * 168 + (bid >> 3);   // XCD swizzle, 1344 = 8*168
    const int n  = orig / 84;                        // 84 = 28*3
    const int r  = orig % 84;
    const int pt = r / 3;                            // pix tile 0..27
    const int cb = r % 3;                            // co tile 0..2
    const int wv   = threadIdx.x >> 6;
    const int lane = threadIdx.x & 63;
    const int lr   = lane & 15;
    const int lk   = lane >> 4;

    const __hip_bfloat16* yb = y + ((size_t)n * HW + (size_t)pt * BN) * CH;
    const __hip_bfloat16* ap0 = g_wpw_u + (size_t)(cb * 128 + wv * 32 + lr) * CH + 8 * lk;
    const __hip_bfloat16* ap1 = ap0 + (size_t)16 * CH;

    f32x4 acc[2][7];
    #pragma unroll
    for (int i = 0; i < 2; ++i)
        #pragma unroll
        for (int j = 0; j < 7; ++j) acc[i][j] = (f32x4){0.f, 0.f, 0.f, 0.f};

    bf16x8 areg[2][2][2];                            // [buf][cofrag][kk]
    STAGE(0, 0);
    LOADA(areg[0], 0);
    __syncthreads();                                 // stage(0) + A(0) complete

    #pragma unroll
    for (int kc = 0; kc < 6; ++kc) {
        const int cur = kc & 1;
        if (kc < 5) { STAGE(cur ^ 1, kc + 1); LOADA(areg[cur ^ 1], kc + 1); }
        #pragma unroll
        for (int kk = 0; kk < 2; ++kk) {
            bf16x8 bfr[7];
            #pragma unroll
            for (int j = 0; j < 7; ++j) {
                const int p  = 16 * j + lr;
                const int c8 = (kk * 4 + lk) ^ (p & 7);
                bfr[j] = *reinterpret_cast<const bf16x8*>(&blds[cur][p * 64 + c8 * 8]);
            }
            #pragma unroll
            for (int i = 0; i < 2; ++i)
                #pragma unroll
                for (int j = 0; j < 7; ++j)
                    acc[i][j] = __builtin_amdgcn_mfma_f32_16x16x32_bf16(
                        areg[cur][i][kk], bfr[j], acc[i][j], 0, 0, 0);
        }
        __syncthreads();   // drains next-chunk stage (vmcnt0) + guards dbuf reuse
    }

    // epilogue: D col(lane&15)=pix, row(lk*4+reg)=co
    const float s = g_mx_pw;
    float* ob = out + (size_t)n * CH * HW + (size_t)pt * BN;
    #pragma unroll
    for (int i = 0; i < 2; ++i) {
        const int co0 = cb * 128 + wv * 32 + i * 16 + lk * 4;
        #pragma unroll
        for (int j = 0; j < 7; ++j) {
            const int px = 16 * j + lr;
            #pragma unroll
            for (int rr = 0; rr < 4; ++rr)
                ob[(size_t)(co0 + rr) * HW + px] = acc[i][j][rr] * s;
        }
    }
}

// ---------- fallback: fused kernel (only if ws too small) ----------
__global__ __launch_bounds__(512) void fused_kernel(const float* __restrict__ x,
                                                    float* __restrict__ out) {
    __shared__ __attribute__((aligned(16))) __hip_bfloat16 ylds[64 * CH];
    const int bid  = blockIdx.x;
    const int orig = (bid & 7) * 112 + (bid >> 3);
    const int n = orig / HH, h = orig % HH;
    const float* xn = x + (size_t)n * CH * HW;

    for (int u = threadIdx.x; u < CH * 7; u += 512) {
        const int ci = u / 7;
        const int wc = u % 7;
        const int w0 = wc * 8;
        const float* xp = xn + (size_t)ci * HW;
        const float* wd = g_wdw_eff + ci * 9;
        float acc[8] = {0.f, 0.f, 0.f, 0.f, 0.f, 0.f, 0.f, 0.f};
        #pragma unroll
        for (int dy = -1; dy <= 1; ++dy) {
            const int hh = h + dy;
            if (hh < 0 || hh >= HH) continue;
            const float* row = xp + hh * WW;
            const float4 va = *reinterpret_cast<const float4*>(row + w0);
            const float4 vb = *reinterpret_cast<const float4*>(row + w0 + 4);
            const float left  = (w0 > 0)      ? row[w0 - 1] : 0.f;
            const float right = (w0 + 8 < WW) ? row[w0 + 8] : 0.f;
            const float xv[10] = {left, va.x, va.y, va.z, va.w,
                                  vb.x, vb.y, vb.z, vb.w, right};
            #pragma unroll
            for (int dx = 0; dx < 3; ++dx) {
                const float wvv = wd[(dy + 1) * 3 + dx];
                #pragma unroll
                for (int j = 0; j < 8; ++j) acc[j] += xv[j + dx] * wvv;
            }
        }
        #pragma unroll
        for (int j = 0; j < 8; ++j)
            ylds[(w0 + j) * CH + (ci ^ ((j ^ wc) << 3))] = __float2bfloat16(acc[j]);
    }
    __syncthreads();

    const int wv   = threadIdx.x >> 6;
    const int lane = threadIdx.x & 63;
    const int lr   = lane & 15;
    const int lk   = lane >> 4;
    f32x4 acc[3][4];
    #pragma unroll
    for (int i = 0; i < 3; ++i)
        #pragma unroll
        for (int j = 0; j < 4; ++j) acc[i][j] = (f32x4){0.f, 0.f, 0.f, 0.f};
    const __hip_bfloat16* abase = g_wpw_u + (size_t)(wv * 16 + lr) * CH + 8 * lk;
    for (int k0 = 0; k0 < CH; k0 += 32) {
        bf16x8 bfr[4];
        #pragma unroll
        for (int j = 0; j < 4; ++j) {
            const int row = 16 * j + lr;
            const int sw  = ((row & 7) ^ ((row >> 3) & 7)) << 3;
            bfr[j] = *reinterpret_cast<const bf16x8*>(&ylds[row * CH + ((k0 + 8 * lk) ^ sw)]);
        }
        #pragma unroll
        for (int i = 0; i < 3; ++i) {
            const bf16x8 afr = *reinterpret_cast<const bf16x8*>(abase + (size_t)(i * 128) * CH + k0);
            #pragma unroll
            for (int j = 0; j < 4; ++j)
                acc[i][j] = __builtin_amdgcn_mfma_f32_16x16x32_bf16(afr, bfr[j], acc[i][j], 0, 0, 0);
        }
    }
    const float s = g_mx_pw;
    float* obase = out + (size_t)n * CH * HW + (size_t)h * WW;
    #pragma unroll
    for (int j = 0; j < 4; ++j) {
        const int pix = 16 * j + lr;
        if (pix >= WW) continue;
        #pragma unroll
        for (int i = 0; i < 3; ++i) {
            const int co0 = (wv + 8 * i) * 16 + lk * 4;
            #pragma unroll
            for (int rr = 0; rr < 4; ++rr)
                obase[(size_t)(co0 + rr) * HW + pix] = acc[i][j][rr] * s;
        }
    }
}

extern "C" void kernel_launch(void* const* d_in, const int* in_sizes, int n_in,
                              void* d_out, int out_size, void* d_ws, size_t ws_size,
                              hipStream_t stream) {
    const float* x    = (const float*)d_in[0];   // (16,384,56,56)
    const float* w_dw = (const float*)d_in[1];   // (384,1,3,3)
    const float* w_pw = (const float*)d_in[2];   // (384,384,1,1)
    float* out = (float*)d_out;

    const size_t y_bytes    = (size_t)NN * HW * CH * sizeof(__hip_bfloat16); // 38.5 MB
    const size_t part_bytes = 96 * sizeof(double);

    if (ws_size >= y_bytes + part_bytes) {
        double* part = (double*)((char*)d_ws + y_bytes);
        partial_kernel<<<96, 256, 0, stream>>>(w_pw, part);
        quant_kernel<<<36, 512, 0, stream>>>(w_dw, w_pw, part);
        __hip_bfloat16* yg = (__hip_bfloat16*)d_ws;   // y[n][pix][ci] bf16
        dw_kernel<<<768, 448, 0, stream>>>(x, yg);
        pw_kernel<<<NN * 28 * 3, 256, 0, stream>>>(yg, out);
    } else if (ws_size >= part_bytes) {
        double* part = (double*)d_ws;
        partial_kernel<<<96, 256, 0, stream>>>(w_pw, part);
        quant_kernel<<<36, 512, 0, stream>>>(w_dw, w_pw, part);
        fused_kernel<<<NN * HH, 512, 0, stream>>>(x, out);
    }
}

// Round 15
// 61.650 us; speedup vs baseline: 1.1099x; 1.1099x over previous
//
#include <hip/hip_runtime.h>
#include <hip/hip_bf16.h>

#define CH 384
#define HH 56
#define WW 56
#define HW (HH*WW)      // 3136 = 28*112
#define NN 16
#define BN 112          // pw pix-tile
#define BK 64           // pw k-chunk

#define XRING 10        // dw ring rows (10 consecutive live rows -> distinct mod 10)
#define XR_STRIDE 3840  // dw ring-row bytes: 240 slots = 16ci x 15 (slot 14 = pad hole)
#define YS_PITCH 18     // dw ys row elems: 16 + 2 pad -> 9-dword stride (odd: bank-rotates)

typedef __attribute__((ext_vector_type(4))) float f32x4;
typedef __attribute__((ext_vector_type(8))) short bf16x8;
typedef __attribute__((ext_vector_type(4))) unsigned int u32x4;

// Prepared weights
__device__ float          g_wdw_eff[CH * 9];   // depthwise: u*mx exact fp32, [o][tap]
__device__ __hip_bfloat16 g_wpw_u[CH * CH];    // pointwise: ternary u exact bf16, [co][ci]
__device__ float          g_mx_pw;             // pointwise scale (epilogue multiply)

// ---------- prep stage A: per-block |w| partial sums + dw weight quant ----------
__global__ __launch_bounds__(256) void partial_kernel(const float* __restrict__ wpw,
                                                      const float* __restrict__ wdw,
                                                      double* __restrict__ part) {
    const int t = threadIdx.x;
    const int base = blockIdx.x * 1536;
    double s = 0.0;
    #pragma unroll
    for (int k = 0; k < 6; ++k) s += (double)fabsf(wpw[base + t + k * 256]);
    #pragma unroll
    for (int off = 32; off > 0; off >>= 1) s += __shfl_down(s, off, 64);
    __shared__ double sred[4];
    if ((t & 63) == 0) sred[t >> 6] = s;
    __syncthreads();
    if (t == 0) part[blockIdx.x] = ((sred[0] + sred[1]) + sred[2]) + sred[3];

    // dw per-channel quant (independent of pw scale): block 0 covers 384 ch
    if (blockIdx.x == 0) {
        for (int c = t; c < CH; c += 256) {
            const float* w = wdw + c * 9;
            float asum = 0.f;
            #pragma unroll
            for (int k = 0; k < 9; ++k) asum += fabsf(w[k]);
            const float mxd = fmaxf(asum / 9.0f, 1e-5f);
            const float scd = 1.0f / mxd;
            #pragma unroll
            for (int k = 0; k < 9; ++k) {
                float u = rintf(w[k] * scd);           // jnp.round == RNE
                u = fminf(1.f, fmaxf(-1.f, u));
                g_wdw_eff[c * 9 + k] = u * mxd;        // exact product
            }
        }
    }
}

// ---------- quant kernel: fallback path only ----------
__global__ __launch_bounds__(512) void quant_kernel(const float* __restrict__ wdw,
                                                    const float* __restrict__ wpw,
                                                    const double* __restrict__ part) {
    const int t = threadIdx.x;
    __shared__ double pl[96];
    __shared__ float s_scale, s_mx;
    if (t < 96) pl[t] = part[t];
    __syncthreads();
    if (t == 0) {
        double tot = 0.0;
        #pragma unroll
        for (int i = 0; i < 96; ++i) tot += pl[i];
        const float mean = (float)(tot / (double)(CH * CH));
        const float mx   = fmaxf(mean, 1e-5f);
        s_mx = mx;
        s_scale = 1.0f / mx;
    }
    __syncthreads();
    const float scale = s_scale;

    const int base = blockIdx.x * 4096 + t * 8;
    const float4 a = *reinterpret_cast<const float4*>(wpw + base);
    const float4 b = *reinterpret_cast<const float4*>(wpw + base + 4);
    const float vin[8] = {a.x, a.y, a.z, a.w, b.x, b.y, b.z, b.w};
    bf16x8 uo;
    #pragma unroll
    for (int k = 0; k < 8; ++k) {
        float u = rintf(vin[k] * scale);
        u = fminf(1.f, fmaxf(-1.f, u));
        __hip_bfloat16 h = __float2bfloat16(u);
        uo[k] = *reinterpret_cast<short*>(&h);
    }
    *reinterpret_cast<bf16x8*>(g_wpw_u + base) = uo;
    if (blockIdx.x == 0 && t == 0) g_mx_pw = s_mx;
}

// ---------- kernel 1: depthwise v8 (round-12 verbatim pipeline) + quant side-job ----------
// Block = (n, 16-ci group, half): 7 four-row bands, 10-row LDS ring, counted
// vmcnt keeps next item's gload_lds in flight across raw s_barriers.
// Side-job (NEW): each block quantizes its 192-elem slice of wpw using the
// deterministic in-order sum of part[96] (identical in every block). All
// side-job VMEM ops issue BEFORE prologue staging -> oldest in FIFO -> the
// pipeline's counted vmcnt(N) semantics are unchanged.
__global__ __launch_bounds__(448, 5) void dw_kernel(const float* __restrict__ x,
                                                    __hip_bfloat16* __restrict__ y,
                                                    const float* __restrict__ wpw,
                                                    const double* __restrict__ part) {
    __shared__ __attribute__((aligned(16))) char xs[XRING * XR_STRIDE];        // 38400 B
    __shared__ __attribute__((aligned(16))) __hip_bfloat16 ys[224 * YS_PITCH]; // 8064 B

    const int bid  = blockIdx.x;
    const int orig = (bid & 7) * 96 + (bid >> 3);    // XCD swizzle, 768 = 8*96
    const int nc   = orig >> 1;
    const int half = orig & 1;
    const int n    = nc / 24;
    const int cig  = nc % 24;
    const int ci0  = cig * 16;

    const int t    = threadIdx.x;
    const int wv   = t >> 6;
    const int lane = t & 63;

    // ---- side-job: pw weight quant for slice [bid*192, bid*192+192) ----
    {
        double tot = 0.0;
        for (int i = 0; i < 96; ++i) tot += part[i]; // uniform, in-order, deterministic
        const float mean = (float)(tot / (double)(CH * CH));
        const float mx   = fmaxf(mean, 1e-5f);
        if (bid == 0 && t == 0) g_mx_pw = mx;
        if (t < 24) {
            const float qsc = 1.0f / mx;
            const int base = bid * 192 + t * 8;
            const float4 a = *reinterpret_cast<const float4*>(wpw + base);
            const float4 b = *reinterpret_cast<const float4*>(wpw + base + 4);
            const float vin[8] = {a.x, a.y, a.z, a.w, b.x, b.y, b.z, b.w};
            bf16x8 uo;
            #pragma unroll
            for (int k = 0; k < 8; ++k) {
                float u = rintf(vin[k] * qsc);
                u = fminf(1.f, fmaxf(-1.f, u));
                __hip_bfloat16 h = __float2bfloat16(u);
                uo[k] = *reinterpret_cast<short*>(&h);
            }
            *reinterpret_cast<bf16x8*>(g_wpw_u + base) = uo;
        }
    }

    // compute role: t = rw*16 + cil
    const int cil = t & 15;
    const int rw  = t >> 4;                          // 0..27
    const int row = rw / 7;
    const int wc  = rw % 7;
    const int w0  = wc * 8;

    const float* xg = x + ((size_t)n * CH + ci0) * HW;

    float wt[9];
    {
        const float* wdp = g_wdw_eff + (ci0 + cil) * 9;
        #pragma unroll
        for (int k = 0; k < 9; ++k) wt[k] = wdp[k];
    }

    const int hbase = half * 28;

    // ---- prologue: stage logical rows hbase-1 .. hbase+4 (6 ring-rows, 24 issues) ----
    #pragma unroll
    for (int kk = 0; kk < 4; ++kk) {
        const int q = wv + 7 * kk;
        if (q < 24) {
            const int ro  = q >> 2;
            const int sub = q & 3;
            const int R   = hbase - 1 + ro;
            const int rr  = (R + XRING) % XRING;
            const int Rc  = R < 0 ? 0 : (R > HH - 1 ? HH - 1 : R);
            const int s   = sub * 64 + lane;         // ring-row slot 0..255
            const int sci = s / 15;
            const int scl = s - sci * 15;
            if (s < 240 && scl < 14) {               // skip pad-hole + tail lanes
                __builtin_amdgcn_global_load_lds(
                    (const __attribute__((address_space(1))) void*)
                        (xg + (size_t)sci * HW + Rc * WW + scl * 4),
                    (__attribute__((address_space(3))) void*)
                        (xs + rr * XR_STRIDE + sub * 1024),
                    16, 0, 0);
            }
        }
    }

    // ---- 7-item pipeline ----
    #pragma unroll
    for (int i = 0; i < 7; ++i) {
        const int h0 = hbase + i * 4;

        if (i < 6) {
            // stage item i+1's 4 NEW rows: h0+5 .. h0+8 (16 issues)
            const int RB = h0 + 5;
            #pragma unroll
            for (int kk = 0; kk < 3; ++kk) {
                const int q = wv + 7 * kk;
                if (q < 16) {
                    const int ro  = q >> 2;
                    const int sub = q & 3;
                    const int R   = RB + ro;
                    const int rr  = R % XRING;
                    const int Rc  = R > HH - 1 ? HH - 1 : R;
                    const int s   = sub * 64 + lane;
                    const int sci = s / 15;
                    const int scl = s - sci * 15;
                    if (s < 240 && scl < 14) {
                        __builtin_amdgcn_global_load_lds(
                            (const __attribute__((address_space(1))) void*)
                                (xg + (size_t)sci * HW + Rc * WW + scl * 4),
                            (__attribute__((address_space(3))) void*)
                                (xs + rr * XR_STRIDE + sub * 1024),
                            16, 0, 0);
                    }
                }
            }
            // drain item i's loads + prior dump store; keep item i+1's in flight
            if (wv < 2) asm volatile("s_waitcnt vmcnt(3)" ::: "memory");
            else        asm volatile("s_waitcnt vmcnt(2)" ::: "memory");
        } else {
            asm volatile("s_waitcnt vmcnt(0)" ::: "memory");
        }
        __builtin_amdgcn_s_barrier();
        __builtin_amdgcn_sched_barrier(0);

        // ---- compute: out row h = h0+row, 8 px from ring rows h-1..h+1 ----
        const int h   = h0 + row;
        const int rrb = (h0 + XRING - 1) % XRING;    // (h0-1) mod XRING

        float acc[8] = {0.f, 0.f, 0.f, 0.f, 0.f, 0.f, 0.f, 0.f};
        #pragma unroll
        for (int r = 0; r < 3; ++r) {
            int rr = rrb + row + r; if (rr >= XRING) rr -= XRING;
            const char* rowp = xs + rr * XR_STRIDE + (cil * 15 + 2 * wc) * 16;
            const f32x4 f0 = *reinterpret_cast<const f32x4*>(rowp);        // cols w0..w0+3
            const f32x4 f1 = *reinterpret_cast<const f32x4*>(rowp + 16);   // w0+4..w0+7
            const float e0 = (wc > 0) ? *reinterpret_cast<const float*>(rowp - 4) : 0.f;
            const float f8 = *reinterpret_cast<const float*>(rowp + 32);   // col w0+8
            const float x9 = (wc < 6) ? f8 : 0.f;                          // col-56 pad
            const float xv[10] = {e0, f0.x, f0.y, f0.z, f0.w,
                                  f1.x, f1.y, f1.z, f1.w, x9};
            const bool dead = (r == 0 && h == 0) || (r == 2 && h == HH - 1);
            #pragma unroll
            for (int d = 0; d < 3; ++d) {
                const float w3 = dead ? 0.f : wt[r * 3 + d];
                #pragma unroll
                for (int j = 0; j < 8; ++j) acc[j] += w3 * xv[j + d];
            }
        }

        // ---- ys transpose write: static j, odd pitch -> conflict-free ----
        const int pxb = row * WW + w0;
        #pragma unroll
        for (int j = 0; j < 8; ++j)
            ys[(pxb + j) * YS_PITCH + cil] = __float2bfloat16(acc[j]);

        asm volatile("s_waitcnt lgkmcnt(0)" ::: "memory");
        __builtin_amdgcn_s_barrier();
        __builtin_amdgcn_sched_barrier(0);

        // ---- dump: thread = (px, ci-octet); 4x b32 LDS -> one dwordx4 store ----
        {
            const int px  = t >> 1;                  // 0..223
            const int oct = t & 1;
            const unsigned* yp =
                reinterpret_cast<const unsigned*>(ys + px * YS_PITCH + oct * 8);
            u32x4 v;
            v.x = yp[0]; v.y = yp[1]; v.z = yp[2]; v.w = yp[3];
            *reinterpret_cast<u32x4*>(
                y + ((size_t)n * HW + (size_t)h0 * WW + px) * CH + ci0 + oct * 8) = v;
        }
        __builtin_amdgcn_sched_barrier(0);           // pin store before next STAGE (vmcnt FIFO)
    }
}

// ---------- kernel 2: pointwise GEMM, global_load_lds-staged B, dbuf ----------
// (round-12 verbatim)
#define STAGE(B, KC) do {                                                         \
    const int _k0 = (KC) * BK;                                                    \
    _Pragma("unroll")                                                             \
    for (int _i = 0; _i < 4; ++_i) {                                              \
        const int _sb = wv * 4 + _i;                                              \
        if (_sb < 14) {                                                           \
            const int _s  = _sb * 64 + lane;                                      \
            const int _p  = _s >> 3;                                              \
            const int _c8 = (_s & 7) ^ (_p & 7);                                  \
            __builtin_amdgcn_global_load_lds(                                     \
                (const __attribute__((address_space(1))) void*)                  \
                    (yb + (size_t)_p * CH + _k0 + _c8 * 8),                       \
                (__attribute__((address_space(3))) void*)                        \
                    (&blds[(B)][0] + _sb * 512),                                  \
                16, 0, 0);                                                        \
        }                                                                         \
    }                                                                             \
} while (0)

#define LOADA(dst, KC) {                                                          \
    dst[0][0] = *reinterpret_cast<const bf16x8*>(ap0 + (KC) * 64);                \
    dst[0][1] = *reinterpret_cast<const bf16x8*>(ap0 + (KC) * 64 + 32);           \
    dst[1][0] = *reinterpret_cast<const bf16x8*>(ap1 + (KC) * 64);                \
    dst[1][1] = *reinterpret_cast<const bf16x8*>(ap1 + (KC) * 64 + 32); }

__global__ __launch_bounds__(256) void pw_kernel(const __hip_bfloat16* __restrict__ y,
                                                 float* __restrict__ out) {
    __shared__ __attribute__((aligned(16))) __hip_bfloat16 blds[2][BN * BK]; // 2x14336 B

    const int bid  = blockIdx.x;
    const int orig = (bid & 7) * 168 + (bid >> 3);   // XCD swizzle, 1344 = 8*168
    const int n  = orig / 84;                        // 84 = 28*3
    const int r  = orig % 84;
    const int pt = r / 3;                            // pix tile 0..27
    const int cb = r % 3;                            // co tile 0..2
    const int wv   = threadIdx.x >> 6;
    const int lane = threadIdx.x & 63;
    const int lr   = lane & 15;
    const int lk   = lane >> 4;

    const __hip_bfloat16* yb = y + ((size_t)n * HW + (size_t)pt * BN) * CH;
    const __hip_bfloat16* ap0 = g_wpw_u + (size_t)(cb * 128 + wv * 32 + lr) * CH + 8 * lk;
    const __hip_bfloat16* ap1 = ap0 + (size_t)16 * CH;

    f32x4 acc[2][7];
    #pragma unroll
    for (int i = 0; i < 2; ++i)
        #pragma unroll
        for (int j = 0; j < 7; ++j) acc[i][j] = (f32x4){0.f, 0.f, 0.f, 0.f};

    bf16x8 areg[2][2][2];                            // [buf][cofrag][kk]
    STAGE(0, 0);
    LOADA(areg[0], 0);
    __syncthreads();                                 // stage(0) + A(0) complete

    #pragma unroll
    for (int kc = 0; kc < 6; ++kc) {
        const int cur = kc & 1;
        if (kc < 5) { STAGE(cur ^ 1, kc + 1); LOADA(areg[cur ^ 1], kc + 1); }
        #pragma unroll
        for (int kk = 0; kk < 2; ++kk) {
            bf16x8 bfr[7];
            #pragma unroll
            for (int j = 0; j < 7; ++j) {
                const int p  = 16 * j + lr;
                const int c8 = (kk * 4 + lk) ^ (p & 7);
                bfr[j] = *reinterpret_cast<const bf16x8*>(&blds[cur][p * 64 + c8 * 8]);
            }
            #pragma unroll
            for (int i = 0; i < 2; ++i)
                #pragma unroll
                for (int j = 0; j < 7; ++j)
                    acc[i][j] = __builtin_amdgcn_mfma_f32_16x16x32_bf16(
                        areg[cur][i][kk], bfr[j], acc[i][j], 0, 0, 0);
        }
        __syncthreads();   // drains next-chunk stage (vmcnt0) + guards dbuf reuse
    }

    // epilogue: D col(lane&15)=pix, row(lk*4+reg)=co
    const float s = g_mx_pw;
    float* ob = out + (size_t)n * CH * HW + (size_t)pt * BN;
    #pragma unroll
    for (int i = 0; i < 2; ++i) {
        const int co0 = cb * 128 + wv * 32 + i * 16 + lk * 4;
        #pragma unroll
        for (int j = 0; j < 7; ++j) {
            const int px = 16 * j + lr;
            #pragma unroll
            for (int rr = 0; rr < 4; ++rr)
                ob[(size_t)(co0 + rr) * HW + px] = acc[i][j][rr] * s;
        }
    }
}

// ---------- fallback: fused kernel (only if ws too small) ----------
__global__ __launch_bounds__(512) void fused_kernel(const float* __restrict__ x,
                                                    float* __restrict__ out) {
    __shared__ __attribute__((aligned(16))) __hip_bfloat16 ylds[64 * CH];
    const int bid  = blockIdx.x;
    const int orig = (bid & 7) * 112 + (bid >> 3);
    const int n = orig / HH, h = orig % HH;
    const float* xn = x + (size_t)n * CH * HW;

    for (int u = threadIdx.x; u < CH * 7; u += 512) {
        const int ci = u / 7;
        const int wc = u % 7;
        const int w0 = wc * 8;
        const float* xp = xn + (size_t)ci * HW;
        const float* wd = g_wdw_eff + ci * 9;
        float acc[8] = {0.f, 0.f, 0.f, 0.f, 0.f, 0.f, 0.f, 0.f};
        #pragma unroll
        for (int dy = -1; dy <= 1; ++dy) {
            const int hh = h + dy;
            if (hh < 0 || hh >= HH) continue;
            const float* row = xp + hh * WW;
            const float4 va = *reinterpret_cast<const float4*>(row + w0);
            const float4 vb = *reinterpret_cast<const float4*>(row + w0 + 4);
            const float left  = (w0 > 0)      ? row[w0 - 1] : 0.f;
            const float right = (w0 + 8 < WW) ? row[w0 + 8] : 0.f;
            const float xv[10] = {left, va.x, va.y, va.z, va.w,
                                  vb.x, vb.y, vb.z, vb.w, right};
            #pragma unroll
            for (int dx = 0; dx < 3; ++dx) {
                const float wvv = wd[(dy + 1) * 3 + dx];
                #pragma unroll
                for (int j = 0; j < 8; ++j) acc[j] += xv[j + dx] * wvv;
            }
        }
        #pragma unroll
        for (int j = 0; j < 8; ++j)
            ylds[(w0 + j) * CH + (ci ^ ((j ^ wc) << 3))] = __float2bfloat16(acc[j]);
    }
    __syncthreads();

    const int wv   = threadIdx.x >> 6;
    const int lane = threadIdx.x & 63;
    const int lr   = lane & 15;
    const int lk   = lane >> 4;
    f32x4 acc[3][4];
    #pragma unroll
    for (int i = 0; i < 3; ++i)
        #pragma unroll
        for (int j = 0; j < 4; ++j) acc[i][j] = (f32x4){0.f, 0.f, 0.f, 0.f};
    const __hip_bfloat16* abase = g_wpw_u + (size_t)(wv * 16 + lr) * CH + 8 * lk;
    for (int k0 = 0; k0 < CH; k0 += 32) {
        bf16x8 bfr[4];
        #pragma unroll
        for (int j = 0; j < 4; ++j) {
            const int row = 16 * j + lr;
            const int sw  = ((row & 7) ^ ((row >> 3) & 7)) << 3;
            bfr[j] = *reinterpret_cast<const bf16x8*>(&ylds[row * CH + ((k0 + 8 * lk) ^ sw)]);
        }
        #pragma unroll
        for (int i = 0; i < 3; ++i) {
            const bf16x8 afr = *reinterpret_cast<const bf16x8*>(abase + (size_t)(i * 128) * CH + k0);
            #pragma unroll
            for (int j = 0; j < 4; ++j)
                acc[i][j] = __builtin_amdgcn_mfma_f32_16x16x32_bf16(afr, bfr[j], acc[i][j], 0, 0, 0);
        }
    }
    const float s = g_mx_pw;
    float* obase = out + (size_t)n * CH * HW + (size_t)h * WW;
    #pragma unroll
    for (int j = 0; j < 4; ++j) {
        const int pix = 16 * j + lr;
        if (pix >= WW) continue;
        #pragma unroll
        for (int i = 0; i < 3; ++i) {
            const int co0 = (wv + 8 * i) * 16 + lk * 4;
            #pragma unroll
            for (int rr = 0; rr < 4; ++rr)
                obase[(size_t)(co0 + rr) * HW + pix] = acc[i][j][rr] * s;
        }
    }
}

extern "C" void kernel_launch(void* const* d_in, const int* in_sizes, int n_in,
                              void* d_out, int out_size, void* d_ws, size_t ws_size,
                              hipStream_t stream) {
    const float* x    = (const float*)d_in[0];   // (16,384,56,56)
    const float* w_dw = (const float*)d_in[1];   // (384,1,3,3)
    const float* w_pw = (const float*)d_in[2];   // (384,384,1,1)
    float* out = (float*)d_out;

    const size_t y_bytes    = (size_t)NN * HW * CH * sizeof(__hip_bfloat16); // 38.5 MB
    const size_t part_bytes = 96 * sizeof(double);

    if (ws_size >= y_bytes + part_bytes) {
        double* part = (double*)((char*)d_ws + y_bytes);
        partial_kernel<<<96, 256, 0, stream>>>(w_pw, w_dw, part);
        __hip_bfloat16* yg = (__hip_bfloat16*)d_ws;   // y[n][pix][ci] bf16
        dw_kernel<<<768, 448, 0, stream>>>(x, yg, w_pw, part);
        pw_kernel<<<NN * 28 * 3, 256, 0, stream>>>(yg, out);
    } else if (ws_size >= part_bytes) {
        double* part = (double*)d_ws;
        partial_kernel<<<96, 256, 0, stream>>>(w_pw, w_dw, part);
        quant_kernel<<<36, 512, 0, stream>>>(w_dw, w_pw, part);
        fused_kernel<<<NN * HH, 512, 0, stream>>>(x, out);
    }
}